// Round 1
// baseline (119.931 us; speedup 1.0000x reference)
//
#include <hip/hip_runtime.h>
#include <math.h>

// SupConLoss reduced algebraically:
//   sum(sim)          = ||sum_i x_i||^2 / T
//   sum(sim*mask)     = sum_c ||S_c||^2 / T,  S_c = sum_{lab==c} x_i  (normalized rows)
//   n_pos             = sum_c n_c^2
// => O(N*H) instead of O(N^2*H). Labels in [0,10).

#define NCLS 10
#define HDIM 768          // fixed by problem shape
#define KPL  (HDIM / 64)  // 12 elems per lane

__global__ void zero_ws(float* __restrict__ g, int n) {
  int i = blockIdx.x * blockDim.x + threadIdx.x;
  if (i < n) g[i] = 0.0f;
}

__global__ __launch_bounds__(512) void class_sums(
    const float* __restrict__ x, const int* __restrict__ lab,
    float* __restrict__ gsum, int rowsPerBlock) {
  __shared__ float cls[NCLS * HDIM];  // 30720 B
  const int tid  = threadIdx.x;
  const int nthr = blockDim.x;
  const int lane = tid & 63;
  const int wave = tid >> 6;
  const int nwaves = nthr >> 6;

  for (int i = tid; i < NCLS * HDIM; i += nthr) cls[i] = 0.0f;
  __syncthreads();

  const int rowsPerWave = rowsPerBlock / nwaves;
  const int rowBase = blockIdx.x * rowsPerBlock + wave * rowsPerWave;

  for (int r = 0; r < rowsPerWave; ++r) {
    const int row = rowBase + r;
    const float* __restrict__ xr = x + (size_t)row * HDIM;
    float v[KPL];
    float ss = 0.0f;
#pragma unroll
    for (int k = 0; k < KPL; ++k) {
      v[k] = xr[lane + 64 * k];   // coalesced: 64 lanes x 4B contiguous
      ss += v[k] * v[k];
    }
    // wave-wide sum of squares (64 lanes)
#pragma unroll
    for (int off = 32; off >= 1; off >>= 1) ss += __shfl_xor(ss, off, 64);
    const float rn = 1.0f / fmaxf(sqrtf(ss), 1e-12f);  // F.normalize clamp
    const int c = lab[row];                            // wave-uniform
    float* __restrict__ dst = cls + c * HDIM;
#pragma unroll
    for (int k = 0; k < KPL; ++k) {
      // addresses lane-consecutive -> 2 lanes/bank, conflict-free (m136)
      atomicAdd(&dst[lane + 64 * k], v[k] * rn);
    }
  }
  __syncthreads();

  for (int i = tid; i < NCLS * HDIM; i += nthr) {
    float p = cls[i];
    if (p != 0.0f) atomicAdd(&gsum[i], p);  // skip classes absent in this block
  }
}

__global__ __launch_bounds__(256) void finalize(
    const float* __restrict__ gsum, const int* __restrict__ lab,
    float* __restrict__ out, int N) {
  __shared__ int cnt[NCLS];
  __shared__ double red0[8];
  __shared__ double red1[8];
  const int tid = threadIdx.x;
  if (tid < NCLS) cnt[tid] = 0;
  __syncthreads();
  for (int i = tid; i < N; i += blockDim.x) atomicAdd(&cnt[lab[i]], 1);
  __syncthreads();

  double masked = 0.0, total = 0.0;
  for (int h = tid; h < HDIM; h += blockDim.x) {
    double t = 0.0;
#pragma unroll
    for (int c = 0; c < NCLS; ++c) {
      double s = (double)gsum[c * HDIM + h];
      masked += s * s;
      t += s;
    }
    total += t * t;
  }
#pragma unroll
  for (int off = 32; off >= 1; off >>= 1) {
    masked += __shfl_xor(masked, off, 64);
    total  += __shfl_xor(total,  off, 64);
  }
  const int lane = tid & 63, wave = tid >> 6;
  if (lane == 0) { red0[wave] = masked; red1[wave] = total; }
  __syncthreads();
  if (tid == 0) {
    double m = 0.0, t = 0.0;
    const int nw = blockDim.x >> 6;
    for (int w = 0; w < nw; ++w) { m += red0[w]; t += red1[w]; }
    double n_pos = 0.0;
    for (int c = 0; c < NCLS; ++c) {
      double cc = (double)cnt[c];
      n_pos += cc * cc;
    }
    const double T = 0.07;
    double nn = (double)N * (double)N;
    double n_neg = nn - n_pos;
    double pos_mean = m / (T * n_pos);
    double neg_mean = (t - m) / (T * n_neg);
    double d = neg_mean - pos_mean;
    // logaddexp(0, d), stable
    double loss = fmax(d, 0.0) + log1p(exp(-fabs(d)));
    out[0] = (float)loss;
  }
}

extern "C" void kernel_launch(void* const* d_in, const int* in_sizes, int n_in,
                              void* d_out, int out_size, void* d_ws, size_t ws_size,
                              hipStream_t stream) {
  const float* x = (const float*)d_in[0];
  const int* lab = (const int*)d_in[1];
  const int N = in_sizes[1];            // 8192
  float* gsum = (float*)d_ws;           // NCLS*HDIM floats = 30720 B

  zero_ws<<<(NCLS * HDIM + 255) / 256, 256, 0, stream>>>(gsum, NCLS * HDIM);

  const int blocks = 256;
  const int rowsPerBlock = N / blocks;  // 32 rows, 4 per wave
  class_sums<<<blocks, 512, 0, stream>>>(x, lab, gsum, rowsPerBlock);

  finalize<<<1, 256, 0, stream>>>(gsum, lab, (float*)d_out, N);
}